// Round 9
// baseline (1277.892 us; speedup 1.0000x reference)
//
#include <hip/hip_runtime.h>
#include <hip/hip_bf16.h>

#define D 48
#define RB 96   // row bytes (48 x fp16); epair.x stores c*RB byte offsets
#define GNUM 64
#define HDIM 128
#define ODIM 12
#define BN_EPS 1e-5f

typedef _Float16 half4v __attribute__((ext_vector_type(4)));
typedef _Float16 half8v __attribute__((ext_vector_type(8)));
typedef float f32x4 __attribute__((ext_vector_type(4)));

// v_mfma_f32_16x16x16_f16: A/B = 4 x f16 per lane, C/D = 4 x f32 per lane.
#define MFMA16(a, b, c) __builtin_amdgcn_mfma_f32_16x16x16f16((a), (b), (c), 0, 0, 0)

// packed fp16 max/min on 8-wide vectors (compiler emits v_pk_max_f16/v_pk_min_f16).
__device__ __forceinline__ half8v h8max(half8v a, half8v b) {
    half8v r;
#pragma unroll
    for (int k = 0; k < 8; ++k) r[k] = a[k] > b[k] ? a[k] : b[k];
    return r;
}
__device__ __forceinline__ half8v h8min(half8v a, half8v b) {
    half8v r;
#pragma unroll
    for (int k = 0; k < 8; ++k) r[k] = a[k] < b[k] ? a[k] : b[k];
    return r;
}
__device__ __forceinline__ half8v h8shfl_xor(half8v v, int mask) {
    union { half8v h; int i[4]; } u;
    u.h = v;
#pragma unroll
    for (int k = 0; k < 4; ++k) u.i[k] = __shfl_xor(u.i[k], mask);
    return u.h;
}

// ---------------- setup kernels ----------------

__global__ __launch_bounds__(256) void k_deg(const int* __restrict__ row, int* __restrict__ deg, int E) {
    int e = blockIdx.x * 256 + threadIdx.x;
    if (e < E) atomicAdd(&deg[row[e]], 1);
}

__global__ __launch_bounds__(256) void k_scan1(const int* __restrict__ deg, int* __restrict__ incl,
                                               int* __restrict__ bsum, float* __restrict__ dinv, int N) {
    __shared__ int s[256];
    int i = blockIdx.x * 256 + threadIdx.x;
    int d = (i < N) ? deg[i] : 0;
    if (i < N) dinv[i] = d > 0 ? rsqrtf((float)d) : 0.f;
    s[threadIdx.x] = d;
    __syncthreads();
    for (int off = 1; off < 256; off <<= 1) {
        int t = (threadIdx.x >= off) ? s[threadIdx.x - off] : 0;
        __syncthreads();
        s[threadIdx.x] += t;
        __syncthreads();
    }
    if (i < N) incl[i] = s[threadIdx.x];
    if (threadIdx.x == 255) bsum[blockIdx.x] = s[255];
}

__global__ __launch_bounds__(512) void k_scan2(int* __restrict__ bsum, int nb) {
    __shared__ int s[512];
    int t = threadIdx.x;
    s[t] = (t < nb) ? bsum[t] : 0;
    __syncthreads();
    for (int off = 1; off < 512; off <<= 1) {
        int v = (t >= off) ? s[t - off] : 0;
        __syncthreads();
        s[t] += v;
        __syncthreads();
    }
    if (t < nb) bsum[t] = s[t];
}

__global__ __launch_bounds__(256) void k_scan3(const int* __restrict__ incl, const int* __restrict__ bsum,
                                               int* __restrict__ rowptr, int N) {
    int i = blockIdx.x * 256 + threadIdx.x;
    if (i < N) {
        int add = (blockIdx.x > 0) ? bsum[blockIdx.x - 1] : 0;
        rowptr[i + 1] = incl[i] + add;
    }
    if (i == 0) rowptr[0] = 0;
}

// XCD-partitioned CSR fill (round-3 best), range-chunked. epair.x = col * RB
// (precomputed byte offset kills the per-gather mul chain in all 3 gather kernels).
__global__ __launch_bounds__(256) void k_fill(const int* __restrict__ row, const int* __restrict__ col,
                                              const int* __restrict__ rowptr, int* __restrict__ fillc,
                                              const float* __restrict__ dinv, int2* __restrict__ epair,
                                              int e0, int e1, int N) {
    int part = blockIdx.x & 7;
    int sub = blockIdx.x >> 3;
    int nsub = (int)(gridDim.x >> 3);
    int lo = (int)(((long long)N * part) >> 3);
    int hi = (int)(((long long)N * (part + 1)) >> 3);
    for (int e = e0 + sub * 256 + threadIdx.x; e < e1; e += nsub * 256) {
        int r = row[e];
        if (r >= lo && r < hi) {
            int c = col[e];
            int p = rowptr[r] + atomicAdd(&fillc[r], 1);
            epair[p] = make_int2(c * RB, __float_as_int(dinv[c]));
        }
    }
}

__global__ __launch_bounds__(256) void k_cvt(const float* __restrict__ x, _Float16* __restrict__ xh, int n4) {
    int i = blockIdx.x * 256 + threadIdx.x;
    if (i < n4) {
        float4 v = ((const float4*)x)[i];
        half4v h;
        h.x = (_Float16)v.x; h.y = (_Float16)v.y; h.z = (_Float16)v.z; h.w = (_Float16)v.w;
        ((half4v*)xh)[i] = h;
    }
}

// Precompute MFMA B-fragments of W in exact lane order, once.
__global__ __launch_bounds__(256) void k_wb(const float* __restrict__ W, _Float16* __restrict__ WB) {
    int idx = blockIdx.x * 256 + threadIdx.x;
    if (idx < 27 * 64) {
        int lane = idx & 63, ct = idx >> 6;
        int c = ct / 3, tl = ct % 3;
        int col = lane & 15, kg = lane >> 4;
        half4v h;
#pragma unroll
        for (int j = 0; j < 4; ++j) h[j] = (_Float16)W[(c * 16 + kg * 4 + j) * 48 + tl * 16 + col];
        *(half4v*)(WB + (size_t)idx * 4) = h;
    }
}

// ---------------- gather kernels: 8 slots x 8 lanes, dwordx4 per lane ----------------
// Lane j<6 reads bytes [j*16, j*16+16) of the 96B row; j=6,7 clamp to j=5 (merged).
// Addresses: byte-offset from epair.x + jbB immediate (no mul in the loop).

#define GATHER_REDUCE8(A)                                             \
    A##0 += __shfl_xor(A##0, 8);  A##1 += __shfl_xor(A##1, 8);        \
    A##2 += __shfl_xor(A##2, 8);  A##3 += __shfl_xor(A##3, 8);        \
    A##4 += __shfl_xor(A##4, 8);  A##5 += __shfl_xor(A##5, 8);        \
    A##6 += __shfl_xor(A##6, 8);  A##7 += __shfl_xor(A##7, 8);        \
    A##0 += __shfl_xor(A##0, 16); A##1 += __shfl_xor(A##1, 16);       \
    A##2 += __shfl_xor(A##2, 16); A##3 += __shfl_xor(A##3, 16);       \
    A##4 += __shfl_xor(A##4, 16); A##5 += __shfl_xor(A##5, 16);       \
    A##6 += __shfl_xor(A##6, 16); A##7 += __shfl_xor(A##7, 16);       \
    A##0 += __shfl_xor(A##0, 32); A##1 += __shfl_xor(A##1, 32);       \
    A##2 += __shfl_xor(A##2, 32); A##3 += __shfl_xor(A##3, 32);       \
    A##4 += __shfl_xor(A##4, 32); A##5 += __shfl_xor(A##5, 32);       \
    A##6 += __shfl_xor(A##6, 32); A##7 += __shfl_xor(A##7, 32);

__global__ __launch_bounds__(256) void k_lhat(const _Float16* __restrict__ cur, const int* __restrict__ rowptr,
                                              const int2* __restrict__ epair, const float* __restrict__ dinv,
                                              _Float16* __restrict__ tx1, int N) {
    int lane = threadIdx.x & 63;
    int i = (blockIdx.x * 256 + threadIdx.x) >> 6;
    if (i >= N) return;
    int slot = lane >> 3, j = lane & 7;
    int jbB = (j < 6 ? j : 5) * 16;   // byte offset within row
    const char* base = (const char*)cur + jbB;
    int s = rowptr[i], e = rowptr[i + 1];
    float a0 = 0.f, a1 = 0.f, a2 = 0.f, a3 = 0.f, a4 = 0.f, a5 = 0.f, a6 = 0.f, a7 = 0.f;
    int p = s + slot;
    for (; p + 8 < e; p += 16) {
        int2 ea = epair[p], eb = epair[p + 8];
        half8v ha = *(const half8v*)(base + (unsigned)ea.x);
        half8v hb = *(const half8v*)(base + (unsigned)eb.x);
        float wa = __int_as_float(ea.y), wb = __int_as_float(eb.y);
        a0 += wa * (float)ha[0] + wb * (float)hb[0];
        a1 += wa * (float)ha[1] + wb * (float)hb[1];
        a2 += wa * (float)ha[2] + wb * (float)hb[2];
        a3 += wa * (float)ha[3] + wb * (float)hb[3];
        a4 += wa * (float)ha[4] + wb * (float)hb[4];
        a5 += wa * (float)ha[5] + wb * (float)hb[5];
        a6 += wa * (float)ha[6] + wb * (float)hb[6];
        a7 += wa * (float)ha[7] + wb * (float)hb[7];
    }
    if (p < e) {
        int2 ea = epair[p];
        half8v ha = *(const half8v*)(base + (unsigned)ea.x);
        float wa = __int_as_float(ea.y);
        a0 += wa * (float)ha[0]; a1 += wa * (float)ha[1]; a2 += wa * (float)ha[2]; a3 += wa * (float)ha[3];
        a4 += wa * (float)ha[4]; a5 += wa * (float)ha[5]; a6 += wa * (float)ha[6]; a7 += wa * (float)ha[7];
    }
    GATHER_REDUCE8(a)
    if (slot == 0 && j < 6) {
        float sc = -dinv[i];
        half8v o;
        o[0] = (_Float16)(sc * a0); o[1] = (_Float16)(sc * a1);
        o[2] = (_Float16)(sc * a2); o[3] = (_Float16)(sc * a3);
        o[4] = (_Float16)(sc * a4); o[5] = (_Float16)(sc * a5);
        o[6] = (_Float16)(sc * a6); o[7] = (_Float16)(sc * a7);
        *(half8v*)((char*)tx1 + (size_t)i * RB + jbB) = o;
    }
}

__global__ __launch_bounds__(256) void k_gather2(const _Float16* __restrict__ tx0, const _Float16* __restrict__ tx1,
                                                 const int* __restrict__ rowptr, const int2* __restrict__ epair,
                                                 const float* __restrict__ dinv, _Float16* __restrict__ tx2, int N) {
    int lane = threadIdx.x & 63;
    int i = (blockIdx.x * 256 + threadIdx.x) >> 6;
    if (i >= N) return;
    int slot = lane >> 3, j = lane & 7;
    int jbB = (j < 6 ? j : 5) * 16;
    const char* base = (const char*)tx1 + jbB;
    int s = rowptr[i], e = rowptr[i + 1];
    float a0 = 0.f, a1 = 0.f, a2 = 0.f, a3 = 0.f, a4 = 0.f, a5 = 0.f, a6 = 0.f, a7 = 0.f;
    int p = s + slot;
    for (; p + 8 < e; p += 16) {
        int2 ea = epair[p], eb = epair[p + 8];
        half8v ha = *(const half8v*)(base + (unsigned)ea.x);
        half8v hb = *(const half8v*)(base + (unsigned)eb.x);
        float wa = __int_as_float(ea.y), wb = __int_as_float(eb.y);
        a0 += wa * (float)ha[0] + wb * (float)hb[0];
        a1 += wa * (float)ha[1] + wb * (float)hb[1];
        a2 += wa * (float)ha[2] + wb * (float)hb[2];
        a3 += wa * (float)ha[3] + wb * (float)hb[3];
        a4 += wa * (float)ha[4] + wb * (float)hb[4];
        a5 += wa * (float)ha[5] + wb * (float)hb[5];
        a6 += wa * (float)ha[6] + wb * (float)hb[6];
        a7 += wa * (float)ha[7] + wb * (float)hb[7];
    }
    if (p < e) {
        int2 ea = epair[p];
        half8v ha = *(const half8v*)(base + (unsigned)ea.x);
        float wa = __int_as_float(ea.y);
        a0 += wa * (float)ha[0]; a1 += wa * (float)ha[1]; a2 += wa * (float)ha[2]; a3 += wa * (float)ha[3];
        a4 += wa * (float)ha[4]; a5 += wa * (float)ha[5]; a6 += wa * (float)ha[6]; a7 += wa * (float)ha[7];
    }
    GATHER_REDUCE8(a)
    if (slot == 0 && j < 6) {
        float sc = -2.f * dinv[i];
        half8v h0 = *(const half8v*)((const char*)tx0 + (size_t)i * RB + jbB);
        half8v o;
        o[0] = (_Float16)(sc * a0 - (float)h0[0]); o[1] = (_Float16)(sc * a1 - (float)h0[1]);
        o[2] = (_Float16)(sc * a2 - (float)h0[2]); o[3] = (_Float16)(sc * a3 - (float)h0[3]);
        o[4] = (_Float16)(sc * a4 - (float)h0[4]); o[5] = (_Float16)(sc * a5 - (float)h0[5]);
        o[6] = (_Float16)(sc * a6 - (float)h0[6]); o[7] = (_Float16)(sc * a7 - (float)h0[7]);
        *(half8v*)((char*)tx2 + (size_t)i * RB + jbB) = o;
    }
}

// ---------------- dense: t = relu([tx0|tx1|tx2] @ W + b), MFMA + fused BN stats ----------------

__global__ __launch_bounds__(256) void k_dense(const _Float16* __restrict__ tx0, const _Float16* __restrict__ tx1,
                                               const _Float16* __restrict__ tx2, const _Float16* __restrict__ WB,
                                               const float* __restrict__ b, _Float16* __restrict__ tbuf,
                                               float* __restrict__ bnst, int N) {
    __shared__ float bns[2 * D];
    int t = threadIdx.x;
    if (t < 2 * D) bns[t] = 0.f;
    __syncthreads();

    int lane = t & 63, wave = t >> 6;
    int node0 = (blockIdx.x * 4 + wave) * 16;
    if (node0 < N) {
        int col = lane & 15, kg = lane >> 4;
        int nodeA = node0 + col;
        bool inA = nodeA < N;
        const _Float16* __restrict__ Xs[3] = {tx0 + (size_t)nodeA * D, tx1 + (size_t)nodeA * D,
                                              tx2 + (size_t)nodeA * D};
        f32x4 acc0 = {}, acc1 = {}, acc2 = {};
#pragma unroll
        for (int c = 0; c < 9; ++c) {
            half4v a = {};
            if (inA) a = *(const half4v*)(Xs[c / 3] + (c % 3) * 16 + kg * 4);
            half4v b0 = *(const half4v*)(WB + ((size_t)(c * 3 + 0) * 64 + lane) * 4);
            half4v b1 = *(const half4v*)(WB + ((size_t)(c * 3 + 1) * 64 + lane) * 4);
            half4v b2 = *(const half4v*)(WB + ((size_t)(c * 3 + 2) * 64 + lane) * 4);
            acc0 = MFMA16(a, b0, acc0);
            acc1 = MFMA16(a, b1, acc1);
            acc2 = MFMA16(a, b2, acc2);
        }
        float bc0 = b[col], bc1 = b[16 + col], bc2 = b[32 + col];
        float s0 = 0.f, q0 = 0.f, s1 = 0.f, q1 = 0.f, s2 = 0.f, q2 = 0.f;
#pragma unroll
        for (int i = 0; i < 4; ++i) {
            int nd = node0 + kg * 4 + i;
            float v0 = fmaxf(acc0[i] + bc0, 0.f);
            float v1 = fmaxf(acc1[i] + bc1, 0.f);
            float v2 = fmaxf(acc2[i] + bc2, 0.f);
            if (nd < N) {
                _Float16* o = tbuf + (size_t)nd * D;
                o[col] = (_Float16)v0;
                o[16 + col] = (_Float16)v1;
                o[32 + col] = (_Float16)v2;
                s0 += v0; q0 += v0 * v0;
                s1 += v1; q1 += v1 * v1;
                s2 += v2; q2 += v2 * v2;
            }
        }
        s0 += __shfl_xor(s0, 16); s0 += __shfl_xor(s0, 32);
        q0 += __shfl_xor(q0, 16); q0 += __shfl_xor(q0, 32);
        s1 += __shfl_xor(s1, 16); s1 += __shfl_xor(s1, 32);
        q1 += __shfl_xor(q1, 16); q1 += __shfl_xor(q1, 32);
        s2 += __shfl_xor(s2, 16); s2 += __shfl_xor(s2, 32);
        q2 += __shfl_xor(q2, 16); q2 += __shfl_xor(q2, 32);
        if (lane < 16) {
            atomicAdd(&bns[col], s0);      atomicAdd(&bns[D + col], q0);
            atomicAdd(&bns[16 + col], s1); atomicAdd(&bns[D + 16 + col], q1);
            atomicAdd(&bns[32 + col], s2); atomicAdd(&bns[D + 32 + col], q2);
        }
    }
    __syncthreads();
    if (t < 2 * D) atomicAdd(&bnst[t], bns[t]);
}

// ---------------- pool: packed-fp16 max/min gather (exact), BN in epilogue ----------------

__global__ __launch_bounds__(256) void k_pool(const _Float16* __restrict__ tbuf, const int* __restrict__ rowptr,
                                              const int2* __restrict__ epair, const float* __restrict__ bnst,
                                              const float* __restrict__ gamma, const float* __restrict__ beta,
                                              float Ninv, _Float16* __restrict__ outh, int N) {
    __shared__ float ssL[2 * D];
    int t = threadIdx.x;
    if (t < D) {
        float mean = bnst[t] * Ninv;
        float var = fmaxf(bnst[D + t] * Ninv - mean * mean, 0.f);
        float sc = gamma[t] * rsqrtf(var + BN_EPS);
        ssL[t] = sc;
        ssL[D + t] = beta[t] - mean * sc;
    }
    __syncthreads();
    int lane = t & 63;
    int i = (blockIdx.x * 256 + t) >> 6;
    if (i >= N) return;
    int slot = lane >> 3, j = lane & 7;
    int jbB = (j < 6 ? j : 5) * 16;
    const char* base = (const char*)tbuf + jbB;
    int s = rowptr[i], e = rowptr[i + 1];
    half8v m, n;
#pragma unroll
    for (int k = 0; k < 8; ++k) { m[k] = (_Float16)(-60000.f); n[k] = (_Float16)(60000.f); }
    int p = s + slot;
    for (; p + 8 < e; p += 16) {
        int oa = epair[p].x, ob = epair[p + 8].x;
        half8v ha = *(const half8v*)(base + (unsigned)oa);
        half8v hb = *(const half8v*)(base + (unsigned)ob);
        m = h8max(m, h8max(ha, hb));
        n = h8min(n, h8min(ha, hb));
    }
    if (p < e) {
        half8v ha = *(const half8v*)(base + (unsigned)epair[p].x);
        m = h8max(m, ha);
        n = h8min(n, ha);
    }
    m = h8max(m, h8shfl_xor(m, 8));
    n = h8min(n, h8shfl_xor(n, 8));
    m = h8max(m, h8shfl_xor(m, 16));
    n = h8min(n, h8shfl_xor(n, 16));
    m = h8max(m, h8shfl_xor(m, 32));
    n = h8min(n, h8shfl_xor(n, 32));
    if (slot == 0 && j < 6) {
        int jb = (j < 6 ? j : 5) * 8;
        half8v o;
        if (s == e) {
#pragma unroll
            for (int k = 0; k < 8; ++k) o[k] = (_Float16)0.f;
        } else {
#pragma unroll
            for (int k = 0; k < 8; ++k) {
                float sc = ssL[jb + k], sh = ssL[D + jb + k];
                float v = (sc >= 0.f) ? sc * (float)m[k] + sh : sc * (float)n[k] + sh;
                o[k] = (_Float16)v;
            }
        }
        *(half8v*)((char*)outh + (size_t)i * RB + jbB) = o;
    }
}

// ---------------- final pooling + MLP ----------------

__global__ __launch_bounds__(256) void k_gpool(const _Float16* __restrict__ outh, const int* __restrict__ batch,
                                               float* __restrict__ g, int N, int chunk) {
    int lane = threadIdx.x & 63;
    int wid = (blockIdx.x * 256 + threadIdx.x) >> 6;
    int start = wid * chunk;
    if (start >= N || lane >= 12) return;
    int end = start + chunk;
    if (end > N) end = N;
    int curb = batch[start];
    float a0 = 0.f, a1 = 0.f, a2 = 0.f, a3 = 0.f;
    for (int i = start; i < end; ++i) {
        int bi = batch[i];
        if (bi != curb) {
            atomicAdd(&g[curb * D + lane * 4 + 0], a0); atomicAdd(&g[curb * D + lane * 4 + 1], a1);
            atomicAdd(&g[curb * D + lane * 4 + 2], a2); atomicAdd(&g[curb * D + lane * 4 + 3], a3);
            curb = bi; a0 = a1 = a2 = a3 = 0.f;
        }
        half4v h = *(const half4v*)(outh + (size_t)i * D + lane * 4);
        a0 += (float)h.x; a1 += (float)h.y; a2 += (float)h.z; a3 += (float)h.w;
    }
    atomicAdd(&g[curb * D + lane * 4 + 0], a0); atomicAdd(&g[curb * D + lane * 4 + 1], a1);
    atomicAdd(&g[curb * D + lane * 4 + 2], a2); atomicAdd(&g[curb * D + lane * 4 + 3], a3);
}

__global__ __launch_bounds__(256) void k_mlp(const float* __restrict__ g, const float* __restrict__ W1,
                                             const float* __restrict__ b1, const float* __restrict__ W2,
                                             const float* __restrict__ b2, float* __restrict__ out) {
    __shared__ float gL[GNUM * D];
    __shared__ float hL[GNUM * HDIM];
    __shared__ float W1L[D * HDIM];
    int t = threadIdx.x;
    for (int i = t; i < GNUM * D; i += 256) gL[i] = g[i];
    for (int i = t; i < D * HDIM; i += 256) W1L[i] = W1[i];
    __syncthreads();
    for (int i = t; i < GNUM * HDIM; i += 256) {
        int gi = i >> 7, hj = i & 127;
        float a = b1[hj];
        for (int k = 0; k < D; ++k) a += gL[gi * D + k] * W1L[k * HDIM + hj];
        hL[i] = fmaxf(a, 0.f);
    }
    __syncthreads();
    for (int i = t; i < GNUM * ODIM; i += 256) {
        int gi = i / ODIM, oj = i % ODIM;
        float a = b2[oj];
        for (int k = 0; k < HDIM; ++k) a += hL[gi * HDIM + k] * W2[k * ODIM + oj];
        out[i] = a;
    }
}

// ---------------- launch ----------------

extern "C" void kernel_launch(void* const* d_in, const int* in_sizes, int n_in,
                              void* d_out, int out_size, void* d_ws, size_t ws_size,
                              hipStream_t stream) {
    const float* x     = (const float*)d_in[0];
    const int*   ei    = (const int*)d_in[1];
    const int*   batch = (const int*)d_in[2];
    const float* W     = (const float*)d_in[4];
    const float* b     = (const float*)d_in[5];
    const float* gamma = (const float*)d_in[6];
    const float* beta  = (const float*)d_in[7];
    const float* W1    = (const float*)d_in[8];
    const float* b1    = (const float*)d_in[9];
    const float* W2    = (const float*)d_in[10];
    const float* b2    = (const float*)d_in[11];

    int N = in_sizes[0] / D;
    int E = in_sizes[1] / 2;
    const int* row = ei;
    const int* col = ei + E;

    char* w = (char*)d_ws;
    auto alloc = [&](size_t bytes) { char* p = w; w += (bytes + 255) & ~(size_t)255; return p; };
    int*       deg     = (int*)alloc((size_t)N * 4);
    float*     dinv    = (float*)alloc((size_t)N * 4);
    int*       fillc   = (int*)alloc((size_t)N * 4);
    int*       incl    = (int*)alloc((size_t)N * 4);
    int*       bsum    = (int*)alloc(4096);
    int*       rowptr  = (int*)alloc((size_t)(N + 1) * 4);
    int2*      epair   = (int2*)alloc((size_t)E * 8);
    _Float16*  xh      = (_Float16*)alloc((size_t)N * D * 2 + 64);
    _Float16*  tx1h    = (_Float16*)alloc((size_t)N * D * 2 + 64);
    _Float16*  tx2h    = (_Float16*)alloc((size_t)N * D * 2 + 64);
    _Float16*  tbufh   = (_Float16*)alloc((size_t)N * D * 2 + 64);
    _Float16*  outh    = (_Float16*)alloc((size_t)N * D * 2 + 64);
    _Float16*  WB      = (_Float16*)alloc(27 * 64 * 4 * 2);
    float*     bnstats = (float*)alloc(5 * 2 * D * 4);   // per-step slices, zeroed once
    float*     g       = (float*)alloc((size_t)GNUM * D * 4);

    (void)hipMemsetAsync(deg, 0, (size_t)N * 4, stream);
    (void)hipMemsetAsync(fillc, 0, (size_t)N * 4, stream);
    (void)hipMemsetAsync(bnstats, 0, 5 * 2 * D * 4, stream);
    (void)hipMemsetAsync(g, 0, (size_t)GNUM * D * 4, stream);

    int nbE = (E + 255) / 256;
    int nbN = (N + 255) / 256;

    k_deg<<<nbE, 256, 0, stream>>>(row, deg, E);
    k_scan1<<<nbN, 256, 0, stream>>>(deg, incl, bsum, dinv, N);
    k_scan2<<<1, 512, 0, stream>>>(bsum, nbN);
    k_scan3<<<nbN, 256, 0, stream>>>(incl, bsum, rowptr, N);
    int E3 = E / 3;
    k_fill<<<2048, 256, 0, stream>>>(row, col, rowptr, fillc, dinv, epair, 0, E3, N);
    k_fill<<<2048, 256, 0, stream>>>(row, col, rowptr, fillc, dinv, epair, E3, 2 * E3, N);
    k_fill<<<2048, 256, 0, stream>>>(row, col, rowptr, fillc, dinv, epair, 2 * E3, E, N);
    int n4 = N * D / 4;
    k_cvt<<<(n4 + 255) / 256, 256, 0, stream>>>(x, xh, n4);
    k_wb<<<7, 256, 0, stream>>>(W, WB);

    int nbWave = (N * 64 + 255) / 256;
    int nbDense = (((N + 15) / 16) + 3) / 4;  // 16-node tiles, 4 waves/block
    float Ninv = 1.f / (float)N;
    const _Float16* cur = xh;
    for (int step = 0; step < 5; ++step) {
        float* bnst = bnstats + step * 2 * D;
        k_lhat<<<nbWave, 256, 0, stream>>>(cur, rowptr, epair, dinv, tx1h, N);
        k_gather2<<<nbWave, 256, 0, stream>>>(cur, tx1h, rowptr, epair, dinv, tx2h, N);
        k_dense<<<nbDense, 256, 0, stream>>>(cur, tx1h, tx2h, WB, b, tbufh, bnst, N);
        k_pool<<<nbWave, 256, 0, stream>>>(tbufh, rowptr, epair, bnst, gamma, beta, Ninv, outh, N);
        cur = outh;
    }

    int chunk = 32;
    int nwaves = (N + chunk - 1) / chunk;
    int nbG = (nwaves * 64 + 255) / 256;
    k_gpool<<<nbG, 256, 0, stream>>>(outh, batch, g, N, chunk);
    k_mlp<<<1, 256, 0, stream>>>(g, W1, b1, W2, b2, (float*)d_out);
}